// Round 13
// baseline (126.936 us; speedup 1.0000x reference)
//
#include <hip/hip_runtime.h>
#include <math.h>

// NetVLAD on MI355X via bf16 hi/lo-split MFMA (3-product emulated fp32).
// N=128 images, C=256 channels, K=64 clusters, P=1024 pixels.
// R13: monolith split into two LDS-free, barrier-free, (almost) atomic-free
// streaming kernels with a packed-a' workspace handoff (33.5 MB):
//  P1 (1024 blocks = image x eighth): GEMM1 direct-from-global + in-register
//     softmax; stores a' = a*rn as packed (hi16|lo16) split to ws; asum via
//     shfl-reduce + small atomics.
//  P2 (512 blocks = image x c-quarter): agg[k][c] = a' @ x^T, both operands
//     direct from global (x read once total: c-partitioned; a' L2/L3-hot),
//     output exclusively owned -> plain coalesced stores, NO atomics, no
//     67MB RMW write amplification.
// MFMA 16x16x32 bf16: A row=l15,k=8*lg4+j; B col=l15,same k;
//                     C col=l15,row=4*lg4+reg  (verified R2-R12)

#define EPSF 1e-12f

typedef __attribute__((ext_vector_type(8))) __bf16 bf16x8;
typedef __attribute__((ext_vector_type(4))) float f32x4;
typedef __attribute__((ext_vector_type(4))) unsigned int u32x4;

#define MFMA(a, b, c) __builtin_amdgcn_mfma_f32_16x16x32_bf16((a), (b), (c), 0, 0, 0)

__device__ __forceinline__ bf16x8 as_bf(u32x4 v) { return __builtin_bit_cast(bf16x8, v); }

// f32 -> packed (hi_bf16 << 16) | lo_bf16  (truncation split, err ~2^-16|x|)
__device__ __forceinline__ unsigned packsplit(float x) {
    const unsigned u  = __float_as_uint(x);
    const unsigned hi = u & 0xFFFF0000u;
    const float lof   = x - __uint_as_float(hi);
    return hi | (__float_as_uint(lof) >> 16);
}

struct u32pair { unsigned h, l; };

// two f32 -> hi-pair u32 and lo-pair u32 (bf16x2 each, elem order f0,f1)
__device__ __forceinline__ u32pair splitpair(float f0, float f1) {
    const unsigned u0 = __float_as_uint(f0), u1 = __float_as_uint(f1);
    u32pair r;
    r.h = __builtin_amdgcn_perm(u1, u0, 0x07060302u);
    const float l0 = f0 - __uint_as_float(u0 & 0xFFFF0000u);
    const float l1 = f1 - __uint_as_float(u1 & 0xFFFF0000u);
    r.l = __builtin_amdgcn_perm(__float_as_uint(l1), __float_as_uint(l0), 0x07060302u);
    return r;
}

// 8 packed u32 (two aligned quads) -> (hi,lo) MFMA operand pair
__device__ __forceinline__ void unpack2q(const u32x4 q0, const u32x4 q1,
                                         u32x4& hi, u32x4& lo) {
    hi[0] = __builtin_amdgcn_perm(q0[1], q0[0], 0x07060302u);
    lo[0] = __builtin_amdgcn_perm(q0[1], q0[0], 0x05040100u);
    hi[1] = __builtin_amdgcn_perm(q0[3], q0[2], 0x07060302u);
    lo[1] = __builtin_amdgcn_perm(q0[3], q0[2], 0x05040100u);
    hi[2] = __builtin_amdgcn_perm(q1[1], q1[0], 0x07060302u);
    lo[2] = __builtin_amdgcn_perm(q1[1], q1[0], 0x05040100u);
    hi[3] = __builtin_amdgcn_perm(q1[3], q1[2], 0x07060302u);
    lo[3] = __builtin_amdgcn_perm(q1[3], q1[2], 0x05040100u);
}

__device__ __forceinline__ void split8v(const float* xv, u32x4& hi, u32x4& lo) {
    #pragma unroll
    for (int w2 = 0; w2 < 4; ++w2) {
        const u32pair r = splitpair(xv[2*w2], xv[2*w2+1]);
        hi[w2] = r.h;
        lo[w2] = r.l;
    }
}

// ---- prep: split W into MFMA-A-fragment-ordered hi/lo arrays in ws.
__global__ void split_w_kernel(const float* __restrict__ wmat,
                               unsigned* __restrict__ whiG,
                               unsigned* __restrict__ wloG) {
    const int idx = blockIdx.x * 256 + threadIdx.x;   // 2048 total
    const int mt = idx >> 9, s = (idx >> 6) & 7, l = idx & 63;
    const int k = mt * 16 + (l & 15);
    const int cb = s * 32 + 8 * (l >> 4);
    const float* wr = wmat + k * 256 + cb;
    const float4 f0 = *(const float4*)wr;
    const float4 f1 = *(const float4*)(wr + 4);
    const float xv[8] = {f0.x, f0.y, f0.z, f0.w, f1.x, f1.y, f1.z, f1.w};
    u32x4 hi, lo; split8v(xv, hi, lo);
    *(u32x4*)(whiG + idx * 4) = hi;
    *(u32x4*)(wloG + idx * 4) = lo;
}

// ================= P1: logits + softmax -> packed a' = a*rn ================
__global__ __launch_bounds__(256, 4) void netvlad_p1(
    const float* __restrict__ x,
    const unsigned* __restrict__ whiG, const unsigned* __restrict__ wloG,
    const float* __restrict__ bias, unsigned* __restrict__ aG,
    float* __restrict__ asum_g) {

    const int t = threadIdx.x;
    const int w = t >> 6, l = t & 63;
    const int l15 = l & 15, lg4 = l >> 4;
    const int n = blockIdx.x & 127, e = blockIdx.x >> 7;
    const size_t ximg = (size_t)n * 256 * 1024;
    const int p0 = e * 128;
    const int cs = lg4 * 8;

    // wave = 32 pixels (2 tiles of 16) x all 64 clusters; LDS-free.
    f32x4 acc1[4][2];
    #pragma unroll
    for (int i = 0; i < 4; ++i) {
        acc1[i][0] = f32x4{0.f, 0.f, 0.f, 0.f};
        acc1[i][1] = f32x4{0.f, 0.f, 0.f, 0.f};
    }
    float ssa[2] = {0.f, 0.f};

    #pragma unroll
    for (int s = 0; s < 8; ++s) {
        u32x4 wh[4], wl[4];
        #pragma unroll
        for (int mt = 0; mt < 4; ++mt) {
            const int fo = ((mt * 8 + s) * 64 + l) * 4;
            wh[mt] = *(const u32x4*)(whiG + fo);
            wl[mt] = *(const u32x4*)(wloG + fo);
        }
        #pragma unroll
        for (int ntl = 0; ntl < 2; ++ntl) {
            const float* bp = x + ximg + (size_t)(s * 32 + cs) * 1024
                              + p0 + (2 * w + ntl) * 16 + l15;
            float xv[8];
            #pragma unroll
            for (int j = 0; j < 8; ++j) xv[j] = bp[(size_t)j * 1024];
            #pragma unroll
            for (int j = 0; j < 8; ++j) ssa[ntl] = fmaf(xv[j], xv[j], ssa[ntl]);
            u32x4 bhi, blo; split8v(xv, bhi, blo);
            #pragma unroll
            for (int mt = 0; mt < 4; ++mt) {
                acc1[mt][ntl] = MFMA(as_bf(wh[mt]), as_bf(bhi), acc1[mt][ntl]);
                acc1[mt][ntl] = MFMA(as_bf(wh[mt]), as_bf(blo), acc1[mt][ntl]);
                acc1[mt][ntl] = MFMA(as_bf(wl[mt]), as_bf(bhi), acc1[mt][ntl]);
            }
        }
    }
    #pragma unroll
    for (int ntl = 0; ntl < 2; ++ntl) {
        ssa[ntl] += __shfl_xor(ssa[ntl], 16);
        ssa[ntl] += __shfl_xor(ssa[ntl], 32);
    }

    f32x4 biasv[4];
    #pragma unroll
    for (int mt = 0; mt < 4; ++mt)
        biasv[mt] = *(const f32x4*)(bias + mt * 16 + 4 * lg4);

    float asum_loc[16];
    #pragma unroll
    for (int i = 0; i < 16; ++i) asum_loc[i] = 0.f;

    // softmax fully in-register; store packed a' = a*rn
    #pragma unroll
    for (int ntl = 0; ntl < 2; ++ntl) {
        const int p = p0 + (2 * w + ntl) * 16 + l15;
        const float rn = 1.f / fmaxf(sqrtf(ssa[ntl]), EPSF);
        float lgv[16];
        #pragma unroll
        for (int mt = 0; mt < 4; ++mt)
            #pragma unroll
            for (int r = 0; r < 4; ++r)
                lgv[mt * 4 + r] = fmaf(acc1[mt][ntl][r], rn, biasv[mt][r]);
        float mx = lgv[0];
        #pragma unroll
        for (int i = 1; i < 16; ++i) mx = fmaxf(mx, lgv[i]);
        mx = fmaxf(mx, __shfl_xor(mx, 16));
        mx = fmaxf(mx, __shfl_xor(mx, 32));
        float den = 0.f;
        #pragma unroll
        for (int i = 0; i < 16; ++i) { lgv[i] = __expf(lgv[i] - mx); den += lgv[i]; }
        den += __shfl_xor(den, 16);
        den += __shfl_xor(den, 32);
        const float inv = 1.f / den;
        #pragma unroll
        for (int mt = 0; mt < 4; ++mt)
            #pragma unroll
            for (int r = 0; r < 4; ++r) {
                const float av = lgv[mt * 4 + r] * inv;      // raw a
                asum_loc[mt * 4 + r] += av;
                aG[((size_t)n * 64 + mt * 16 + 4 * lg4 + r) * 1024 + p] =
                    packsplit(av * rn);                      // a' = a*rn
            }
    }

    // asum: reduce each (mt,r) over the wave's 32 pixels (l15 group), atomics
    #pragma unroll
    for (int i = 0; i < 16; ++i) {
        float s = asum_loc[i];
        s += __shfl_xor(s, 1);
        s += __shfl_xor(s, 2);
        s += __shfl_xor(s, 4);
        s += __shfl_xor(s, 8);
        if (l15 == 0)
            atomicAdd(&asum_g[n * 64 + (i >> 2) * 16 + 4 * lg4 + (i & 3)], s);
    }
}

// ================= P2: agg[k][c] = a' @ x^T, output-partitioned =============
__global__ __launch_bounds__(256, 2) void netvlad_p2(
    const float* __restrict__ x, const unsigned* __restrict__ aG,
    float* __restrict__ out) {

    const int t = threadIdx.x;
    const int w = t >> 6, l = t & 63;
    const int l15 = l & 15, lg4 = l >> 4;
    const int n = blockIdx.x >> 2, cq = blockIdx.x & 3;
    const size_t ximg = (size_t)n * 256 * 1024;
    const int cs = lg4 * 8;
    const int c0 = cq * 64 + w * 16;       // wave's 16-channel tile

    const float*    xrow = x  + ximg + (size_t)(c0 + l15) * 1024 + cs;
    const unsigned* ar   = aG + ((size_t)n * 64 + l15) * 1024 + cs;

    f32x4 acc[4];
    #pragma unroll
    for (int mt = 0; mt < 4; ++mt) acc[mt] = f32x4{0.f, 0.f, 0.f, 0.f};

    #pragma unroll 4
    for (int ks = 0; ks < 32; ++ks) {
        // B frag: x[c = c0+l15][p = ks*32+cs+j], contiguous 32B per lane
        float xv[8];
        const float4 f0 = *(const float4*)(xrow + ks * 32);
        const float4 f1 = *(const float4*)(xrow + ks * 32 + 4);
        xv[0]=f0.x; xv[1]=f0.y; xv[2]=f0.z; xv[3]=f0.w;
        xv[4]=f1.x; xv[5]=f1.y; xv[6]=f1.z; xv[7]=f1.w;
        u32x4 bhi, blo; split8v(xv, bhi, blo);
        #pragma unroll
        for (int mt = 0; mt < 4; ++mt) {
            // A frag: a'[k = mt*16+l15][p = ks*32+cs+j], packed, L2/L3-hot
            const unsigned* ap = ar + (size_t)mt * 16 * 1024 + ks * 32;
            const u32x4 pa = *(const u32x4*)ap;
            const u32x4 pb = *(const u32x4*)(ap + 4);
            u32x4 ahi, alo; unpack2q(pa, pb, ahi, alo);
            acc[mt] = MFMA(as_bf(ahi), as_bf(bhi), acc[mt]);
            acc[mt] = MFMA(as_bf(ahi), as_bf(blo), acc[mt]);
            acc[mt] = MFMA(as_bf(alo), as_bf(bhi), acc[mt]);
        }
    }
    // C: col=l15 -> channel c0+l15, row=4*lg4+r -> cluster; exclusive, plain stores
    float* op = out + (size_t)n * 16384;
    #pragma unroll
    for (int mt = 0; mt < 4; ++mt)
        #pragma unroll
        for (int r = 0; r < 4; ++r)
            op[(mt * 16 + 4 * lg4 + r) * 256 + c0 + l15] = acc[mt][r];
}

__global__ __launch_bounds__(256) void netvlad_epi(
    float* __restrict__ out, const float* __restrict__ asum_g,
    const float* __restrict__ cent) {
    __shared__ float wred[4];
    __shared__ float gs_sh;
    const int n = blockIdx.x;
    const int t = threadIdx.x;
    const int k = t >> 2;          // 4 threads per cluster row
    const int q = t & 3;
    float* op = out + (size_t)n * 16384 + k * 256 + q * 64;
    const float* cp = cent + k * 256 + q * 64;
    const float as = asum_g[n * 64 + k];

    float v[64];
    float ss = 0.f;
    #pragma unroll
    for (int i = 0; i < 64; i += 4) {
        const float4 av = *(const float4*)&op[i];
        const float4 cv = *(const float4*)&cp[i];
        v[i+0] = fmaf(-as, cv.x, av.x);
        v[i+1] = fmaf(-as, cv.y, av.y);
        v[i+2] = fmaf(-as, cv.z, av.z);
        v[i+3] = fmaf(-as, cv.w, av.w);
        ss = fmaf(v[i+0], v[i+0], ss);
        ss = fmaf(v[i+1], v[i+1], ss);
        ss = fmaf(v[i+2], v[i+2], ss);
        ss = fmaf(v[i+3], v[i+3], ss);
    }
    ss += __shfl_xor(ss, 1);
    ss += __shfl_xor(ss, 2);
    const float iscale = 1.f / fmaxf(sqrtf(ss), EPSF);

    float gsum = (q == 0) ? ss * iscale * iscale : 0.f;
    #pragma unroll
    for (int off = 4; off < 64; off <<= 1) gsum += __shfl_xor(gsum, off);
    if ((t & 63) == 0) wred[t >> 6] = gsum;
    __syncthreads();
    if (t == 0) {
        const float tot = wred[0] + wred[1] + wred[2] + wred[3];
        gs_sh = 1.f / fmaxf(sqrtf(tot), EPSF);
    }
    __syncthreads();
    const float fs = iscale * gs_sh;
    #pragma unroll
    for (int i = 0; i < 64; i += 4) {
        float4 w4;
        w4.x = v[i+0] * fs; w4.y = v[i+1] * fs;
        w4.z = v[i+2] * fs; w4.w = v[i+3] * fs;
        *(float4*)&op[i] = w4;
    }
}

extern "C" void kernel_launch(void* const* d_in, const int* in_sizes, int n_in,
                              void* d_out, int out_size, void* d_ws, size_t ws_size,
                              hipStream_t stream) {
    (void)in_sizes; (void)n_in; (void)out_size; (void)ws_size;
    const float* x    = (const float*)d_in[0];
    const float* wmat = (const float*)d_in[1];
    const float* b    = (const float*)d_in[2];
    const float* cent = (const float*)d_in[3];
    float* out = (float*)d_out;
    // ws layout: whiG 8192 u32 | wloG 8192 u32 | asum_g 8192 f32 | aG 8.4M u32
    unsigned* whiG = (unsigned*)d_ws;
    unsigned* wloG = whiG + 8192;
    float* asum_g  = (float*)(whiG + 16384);
    unsigned* aG   = whiG + 24576;                 // 128*64*1024 u32 = 33.5 MB

    hipMemsetAsync(asum_g, 0, 128 * 64 * sizeof(float), stream);
    split_w_kernel<<<8, 256, 0, stream>>>(wmat, whiG, wloG);
    netvlad_p1<<<1024, 256, 0, stream>>>(x, whiG, wloG, b, aG, asum_g);
    netvlad_p2<<<512, 256, 0, stream>>>(x, aG, out);
    netvlad_epi<<<128, 256, 0, stream>>>(out, asum_g, cent);
}

// Round 14
// 126.611 us; speedup vs baseline: 1.0026x; 1.0026x over previous
//
#include <hip/hip_runtime.h>
#include <math.h>

// NetVLAD on MI355X via bf16 hi/lo-split MFMA (3-product emulated fp32).
// N=128 images, C=256 channels, K=64 clusters, P=1024 pixels.
// R14: R13 two-kernel split + ILP fix.
//  P1 (1024 blocks = image x eighth): GEMM1 direct-from-global with 1-step
//     register prefetch + in-register softmax; stores a' = a*rn packed to ws;
//     asum block-reduced in 1KB LDS, plain-stored (no atomics, no memset).
//  P2 (1024 blocks = image x c-quarter x pixel-half): agg partials, fully
//     unrolled 16-step K-loop with explicit next-step register prefetch
//     (x frag + 4 a-frag pairs in flight); plain stores to out0/out1.
//  epi: out0+out1 - asum*cent, intra+global normalize.
// MFMA 16x16x32 bf16: A row=l15,k=8*lg4+j; B col=l15,same k;
//                     C col=l15,row=4*lg4+reg  (verified R2-R13)

#define EPSF 1e-12f

typedef __attribute__((ext_vector_type(8))) __bf16 bf16x8;
typedef __attribute__((ext_vector_type(4))) float f32x4;
typedef __attribute__((ext_vector_type(4))) unsigned int u32x4;

#define MFMA(a, b, c) __builtin_amdgcn_mfma_f32_16x16x32_bf16((a), (b), (c), 0, 0, 0)

__device__ __forceinline__ bf16x8 as_bf(u32x4 v) { return __builtin_bit_cast(bf16x8, v); }

// f32 -> packed (hi_bf16 << 16) | lo_bf16  (truncation split, err ~2^-16|x|)
__device__ __forceinline__ unsigned packsplit(float x) {
    const unsigned u  = __float_as_uint(x);
    const unsigned hi = u & 0xFFFF0000u;
    const float lof   = x - __uint_as_float(hi);
    return hi | (__float_as_uint(lof) >> 16);
}

struct u32pair { unsigned h, l; };

__device__ __forceinline__ u32pair splitpair(float f0, float f1) {
    const unsigned u0 = __float_as_uint(f0), u1 = __float_as_uint(f1);
    u32pair r;
    r.h = __builtin_amdgcn_perm(u1, u0, 0x07060302u);
    const float l0 = f0 - __uint_as_float(u0 & 0xFFFF0000u);
    const float l1 = f1 - __uint_as_float(u1 & 0xFFFF0000u);
    r.l = __builtin_amdgcn_perm(__float_as_uint(l1), __float_as_uint(l0), 0x07060302u);
    return r;
}

// 8 packed u32 (two aligned quads) -> (hi,lo) MFMA operand pair
__device__ __forceinline__ void unpack2q(const u32x4 q0, const u32x4 q1,
                                         u32x4& hi, u32x4& lo) {
    hi[0] = __builtin_amdgcn_perm(q0[1], q0[0], 0x07060302u);
    lo[0] = __builtin_amdgcn_perm(q0[1], q0[0], 0x05040100u);
    hi[1] = __builtin_amdgcn_perm(q0[3], q0[2], 0x07060302u);
    lo[1] = __builtin_amdgcn_perm(q0[3], q0[2], 0x05040100u);
    hi[2] = __builtin_amdgcn_perm(q1[1], q1[0], 0x07060302u);
    lo[2] = __builtin_amdgcn_perm(q1[1], q1[0], 0x05040100u);
    hi[3] = __builtin_amdgcn_perm(q1[3], q1[2], 0x07060302u);
    lo[3] = __builtin_amdgcn_perm(q1[3], q1[2], 0x05040100u);
}

__device__ __forceinline__ void split8v(const float* xv, u32x4& hi, u32x4& lo) {
    #pragma unroll
    for (int w2 = 0; w2 < 4; ++w2) {
        const u32pair r = splitpair(xv[2*w2], xv[2*w2+1]);
        hi[w2] = r.h;
        lo[w2] = r.l;
    }
}

// ---- prep: split W into MFMA-A-fragment-ordered hi/lo arrays in ws.
__global__ void split_w_kernel(const float* __restrict__ wmat,
                               unsigned* __restrict__ whiG,
                               unsigned* __restrict__ wloG) {
    const int idx = blockIdx.x * 256 + threadIdx.x;   // 2048 total
    const int mt = idx >> 9, s = (idx >> 6) & 7, l = idx & 63;
    const int k = mt * 16 + (l & 15);
    const int cb = s * 32 + 8 * (l >> 4);
    const float* wr = wmat + k * 256 + cb;
    const float4 f0 = *(const float4*)wr;
    const float4 f1 = *(const float4*)(wr + 4);
    const float xv[8] = {f0.x, f0.y, f0.z, f0.w, f1.x, f1.y, f1.z, f1.w};
    u32x4 hi, lo; split8v(xv, hi, lo);
    *(u32x4*)(whiG + idx * 4) = hi;
    *(u32x4*)(wloG + idx * 4) = lo;
}

// ================= P1: logits + softmax -> packed a' = a*rn ================
__global__ __launch_bounds__(256, 4) void netvlad_p1(
    const float* __restrict__ x,
    const unsigned* __restrict__ whiG, const unsigned* __restrict__ wloG,
    const float* __restrict__ bias, unsigned* __restrict__ aG,
    float* __restrict__ asum_part) {

    __shared__ float asum_lds[4][64];
    const int t = threadIdx.x;
    const int w = t >> 6, l = t & 63;
    const int l15 = l & 15, lg4 = l >> 4;
    const int n = blockIdx.x & 127, e = blockIdx.x >> 7;
    const size_t ximg = (size_t)n * 256 * 1024;
    const int p0 = e * 128;
    const int cs = lg4 * 8;

    f32x4 acc1[4][2];
    #pragma unroll
    for (int i = 0; i < 4; ++i) {
        acc1[i][0] = f32x4{0.f, 0.f, 0.f, 0.f};
        acc1[i][1] = f32x4{0.f, 0.f, 0.f, 0.f};
    }
    float ssa[2] = {0.f, 0.f};

    // flat 16 steps (s,ntl) with 1-step x prefetch; W frags reloaded per s.
    #define P1_ADDR(st_) (x + ximg + (size_t)(((st_) >> 1) * 32 + cs) * 1024 \
                          + p0 + (2 * w + ((st_) & 1)) * 16 + l15)
    float nxv[8];
    {
        const float* bp = P1_ADDR(0);
        #pragma unroll
        for (int j = 0; j < 8; ++j) nxv[j] = bp[(size_t)j * 1024];
    }
    u32x4 wh[4], wl[4];
    #pragma unroll
    for (int st = 0; st < 16; ++st) {
        const int s = st >> 1, ntl = st & 1;
        float xv[8];
        #pragma unroll
        for (int j = 0; j < 8; ++j) xv[j] = nxv[j];
        if (st < 15) {
            const float* bp = P1_ADDR(st + 1);
            #pragma unroll
            for (int j = 0; j < 8; ++j) nxv[j] = bp[(size_t)j * 1024];
        }
        if (ntl == 0) {
            #pragma unroll
            for (int mt = 0; mt < 4; ++mt) {
                const int fo = ((mt * 8 + s) * 64 + l) * 4;
                wh[mt] = *(const u32x4*)(whiG + fo);
                wl[mt] = *(const u32x4*)(wloG + fo);
            }
        }
        #pragma unroll
        for (int j = 0; j < 8; ++j) ssa[ntl] = fmaf(xv[j], xv[j], ssa[ntl]);
        u32x4 bhi, blo; split8v(xv, bhi, blo);
        #pragma unroll
        for (int mt = 0; mt < 4; ++mt) {
            acc1[mt][ntl] = MFMA(as_bf(wh[mt]), as_bf(bhi), acc1[mt][ntl]);
            acc1[mt][ntl] = MFMA(as_bf(wh[mt]), as_bf(blo), acc1[mt][ntl]);
            acc1[mt][ntl] = MFMA(as_bf(wl[mt]), as_bf(bhi), acc1[mt][ntl]);
        }
    }
    #pragma unroll
    for (int ntl = 0; ntl < 2; ++ntl) {
        ssa[ntl] += __shfl_xor(ssa[ntl], 16);
        ssa[ntl] += __shfl_xor(ssa[ntl], 32);
    }

    f32x4 biasv[4];
    #pragma unroll
    for (int mt = 0; mt < 4; ++mt)
        biasv[mt] = *(const f32x4*)(bias + mt * 16 + 4 * lg4);

    float asum_loc[16];
    #pragma unroll
    for (int i = 0; i < 16; ++i) asum_loc[i] = 0.f;

    // softmax fully in-register; store packed a' = a*rn
    #pragma unroll
    for (int ntl = 0; ntl < 2; ++ntl) {
        const int p = p0 + (2 * w + ntl) * 16 + l15;
        const float rn = 1.f / fmaxf(sqrtf(ssa[ntl]), EPSF);
        float lgv[16];
        #pragma unroll
        for (int mt = 0; mt < 4; ++mt)
            #pragma unroll
            for (int r = 0; r < 4; ++r)
                lgv[mt * 4 + r] = fmaf(acc1[mt][ntl][r], rn, biasv[mt][r]);
        float mx = lgv[0];
        #pragma unroll
        for (int i = 1; i < 16; ++i) mx = fmaxf(mx, lgv[i]);
        mx = fmaxf(mx, __shfl_xor(mx, 16));
        mx = fmaxf(mx, __shfl_xor(mx, 32));
        float den = 0.f;
        #pragma unroll
        for (int i = 0; i < 16; ++i) { lgv[i] = __expf(lgv[i] - mx); den += lgv[i]; }
        den += __shfl_xor(den, 16);
        den += __shfl_xor(den, 32);
        const float inv = 1.f / den;
        #pragma unroll
        for (int mt = 0; mt < 4; ++mt)
            #pragma unroll
            for (int r = 0; r < 4; ++r) {
                const float av = lgv[mt * 4 + r] * inv;      // raw a
                asum_loc[mt * 4 + r] += av;
                aG[((size_t)n * 64 + mt * 16 + 4 * lg4 + r) * 1024 + p] =
                    packsplit(av * rn);                      // a' = a*rn
            }
    }

    // asum: shfl-reduce over the wave's 32 pixels, LDS-reduce over 4 waves
    #pragma unroll
    for (int i = 0; i < 16; ++i) {
        float s = asum_loc[i];
        s += __shfl_xor(s, 1);
        s += __shfl_xor(s, 2);
        s += __shfl_xor(s, 4);
        s += __shfl_xor(s, 8);
        if (l15 == 0) asum_lds[w][(i >> 2) * 16 + 4 * lg4 + (i & 3)] = s;
    }
    __syncthreads();
    if (t < 64)
        asum_part[((size_t)n * 8 + e) * 64 + t] =
            asum_lds[0][t] + asum_lds[1][t] + asum_lds[2][t] + asum_lds[3][t];
}

// ========== P2: agg partial = a' @ x^T over a pixel half; prefetched =======
__global__ __launch_bounds__(256, 4) void netvlad_p2(
    const float* __restrict__ x, const unsigned* __restrict__ aG,
    float* __restrict__ out0, float* __restrict__ out1) {

    const int t = threadIdx.x;
    const int w = t >> 6, l = t & 63;
    const int l15 = l & 15, lg4 = l >> 4;
    const int n = blockIdx.x & 127;
    const int z = blockIdx.x >> 7;         // 0..7
    const int cq = z & 3, ph = z >> 2;     // c-quarter, pixel-half
    const size_t ximg = (size_t)n * 256 * 1024;
    const int cs = lg4 * 8;
    const int c0 = cq * 64 + w * 16;       // wave's 16-channel tile

    const float*    xrow = x  + ximg + (size_t)(c0 + l15) * 1024 + ph * 512 + cs;
    const unsigned* ar   = aG + ((size_t)n * 64 + l15) * 1024 + ph * 512 + cs;

    f32x4 acc[4];
    #pragma unroll
    for (int mt = 0; mt < 4; ++mt) acc[mt] = f32x4{0.f, 0.f, 0.f, 0.f};

    // 1-step register prefetch: x frag + 4 a-frag pairs in flight
    float4 nf0 = *(const float4*)xrow;
    float4 nf1 = *(const float4*)(xrow + 4);
    u32x4 na[4], nb[4];
    #pragma unroll
    for (int mt = 0; mt < 4; ++mt) {
        na[mt] = *(const u32x4*)(ar + mt * 16384);
        nb[mt] = *(const u32x4*)(ar + mt * 16384 + 4);
    }

    #pragma unroll
    for (int ks = 0; ks < 16; ++ks) {
        const float4 f0 = nf0, f1 = nf1;
        u32x4 ca[4], cb[4];
        #pragma unroll
        for (int mt = 0; mt < 4; ++mt) { ca[mt] = na[mt]; cb[mt] = nb[mt]; }
        if (ks < 15) {
            nf0 = *(const float4*)(xrow + (ks + 1) * 32);
            nf1 = *(const float4*)(xrow + (ks + 1) * 32 + 4);
            #pragma unroll
            for (int mt = 0; mt < 4; ++mt) {
                na[mt] = *(const u32x4*)(ar + mt * 16384 + (ks + 1) * 32);
                nb[mt] = *(const u32x4*)(ar + mt * 16384 + (ks + 1) * 32 + 4);
            }
        }
        float xv[8];
        xv[0]=f0.x; xv[1]=f0.y; xv[2]=f0.z; xv[3]=f0.w;
        xv[4]=f1.x; xv[5]=f1.y; xv[6]=f1.z; xv[7]=f1.w;
        u32x4 bhi, blo; split8v(xv, bhi, blo);
        #pragma unroll
        for (int mt = 0; mt < 4; ++mt) {
            u32x4 ahi, alo; unpack2q(ca[mt], cb[mt], ahi, alo);
            acc[mt] = MFMA(as_bf(ahi), as_bf(bhi), acc[mt]);
            acc[mt] = MFMA(as_bf(ahi), as_bf(blo), acc[mt]);
            acc[mt] = MFMA(as_bf(alo), as_bf(bhi), acc[mt]);
        }
    }
    float* op = (ph ? out1 : out0) + (size_t)n * 16384;
    #pragma unroll
    for (int mt = 0; mt < 4; ++mt)
        #pragma unroll
        for (int r = 0; r < 4; ++r)
            op[(mt * 16 + 4 * lg4 + r) * 256 + c0 + l15] = acc[mt][r];
}

__global__ __launch_bounds__(256) void netvlad_epi(
    float* __restrict__ out, const float* __restrict__ out1,
    const float* __restrict__ asum_part, const float* __restrict__ cent) {
    __shared__ float wred[4];
    __shared__ float gs_sh;
    const int n = blockIdx.x;
    const int t = threadIdx.x;
    const int k = t >> 2;          // 4 threads per cluster row
    const int q = t & 3;
    float* op = out + (size_t)n * 16384 + k * 256 + q * 64;
    const float* o1 = out1 + (size_t)n * 16384 + k * 256 + q * 64;
    const float* cp = cent + k * 256 + q * 64;
    float as = 0.f;
    #pragma unroll
    for (int e2 = 0; e2 < 8; ++e2)
        as += asum_part[((size_t)n * 8 + e2) * 64 + k];

    float v[64];
    float ss = 0.f;
    #pragma unroll
    for (int i = 0; i < 64; i += 4) {
        const float4 a0 = *(const float4*)&op[i];
        const float4 a1 = *(const float4*)&o1[i];
        const float4 cv = *(const float4*)&cp[i];
        v[i+0] = fmaf(-as, cv.x, a0.x + a1.x);
        v[i+1] = fmaf(-as, cv.y, a0.y + a1.y);
        v[i+2] = fmaf(-as, cv.z, a0.z + a1.z);
        v[i+3] = fmaf(-as, cv.w, a0.w + a1.w);
        ss = fmaf(v[i+0], v[i+0], ss);
        ss = fmaf(v[i+1], v[i+1], ss);
        ss = fmaf(v[i+2], v[i+2], ss);
        ss = fmaf(v[i+3], v[i+3], ss);
    }
    ss += __shfl_xor(ss, 1);
    ss += __shfl_xor(ss, 2);
    const float iscale = 1.f / fmaxf(sqrtf(ss), EPSF);

    float gsum = (q == 0) ? ss * iscale * iscale : 0.f;
    #pragma unroll
    for (int off = 4; off < 64; off <<= 1) gsum += __shfl_xor(gsum, off);
    if ((t & 63) == 0) wred[t >> 6] = gsum;
    __syncthreads();
    if (t == 0) {
        const float tot = wred[0] + wred[1] + wred[2] + wred[3];
        gs_sh = 1.f / fmaxf(sqrtf(tot), EPSF);
    }
    __syncthreads();
    const float fs = iscale * gs_sh;
    #pragma unroll
    for (int i = 0; i < 64; i += 4) {
        float4 w4;
        w4.x = v[i+0] * fs; w4.y = v[i+1] * fs;
        w4.z = v[i+2] * fs; w4.w = v[i+3] * fs;
        *(float4*)&op[i] = w4;
    }
}

extern "C" void kernel_launch(void* const* d_in, const int* in_sizes, int n_in,
                              void* d_out, int out_size, void* d_ws, size_t ws_size,
                              hipStream_t stream) {
    (void)in_sizes; (void)n_in; (void)out_size; (void)ws_size;
    const float* x    = (const float*)d_in[0];
    const float* wmat = (const float*)d_in[1];
    const float* b    = (const float*)d_in[2];
    const float* cent = (const float*)d_in[3];
    float* out = (float*)d_out;
    // ws layout (u32 units): whiG 8192 | wloG 8192 | asum_part 65536 |
    //                        aG 8388608 | out1 2097152   (~42.3 MB)
    unsigned* whiG = (unsigned*)d_ws;
    unsigned* wloG = whiG + 8192;
    float* asum_part = (float*)(whiG + 16384);
    unsigned* aG   = whiG + 16384 + 65536;
    float* out1    = (float*)(aG + 8388608);

    split_w_kernel<<<8, 256, 0, stream>>>(wmat, whiG, wloG);
    netvlad_p1<<<1024, 256, 0, stream>>>(x, whiG, wloG, b, aG, asum_part);
    netvlad_p2<<<1024, 256, 0, stream>>>(x, aG, out, out1);
    netvlad_epi<<<128, 256, 0, stream>>>(out, out1, asum_part, cent);
}

// Round 15
// 81.677 us; speedup vs baseline: 1.5541x; 1.5502x over previous
//
#include <hip/hip_runtime.h>
#include <math.h>

// NetVLAD on MI355X via bf16 hi/lo-split MFMA (3-product emulated fp32).
// N=128 images, C=256 channels, K=64 clusters, P=1024 pixels.
// R15: P2 rebuilt around __builtin_amdgcn_global_load_lds (DMA-to-LDS, no
// VGPR round-trip -> loads stay in flight regardless of compiler scheduling).
//  P1 (1024 blocks): unchanged R14 (GEMM1 + in-register softmax -> packed a').
//  P2 (1024 blocks = n x c-quarter x pixel-half): 16 slabs x 32 pixels;
//     per slab stage x[64c][32p] (raw fp32) + a'[64k][32p] (packed) via
//     wave-level global_load_lds dwordx4, double-buffered, 1 barrier/slab,
//     DMA(s+1) overlaps compute(s) (m97 structure). XOR-swizzled:
//     linear LDS dest + inverse-swizzled global src + swizzled ds_read_b128
//     (quad q -> q^(row&7); 16-way conflict -> 2-way). No atomics.
//  epi: out0+out1 - asum*cent, intra+global normalize.
// MFMA 16x16x32 bf16: A row=l15,k=8*lg4+j; B col=l15,same k;
//                     C col=l15,row=4*lg4+reg  (verified R2-R14)

#define EPSF 1e-12f

typedef __attribute__((ext_vector_type(8))) __bf16 bf16x8;
typedef __attribute__((ext_vector_type(4))) float f32x4;
typedef __attribute__((ext_vector_type(4))) unsigned int u32x4;

#define MFMA(a, b, c) __builtin_amdgcn_mfma_f32_16x16x32_bf16((a), (b), (c), 0, 0, 0)

__device__ __forceinline__ bf16x8 as_bf(u32x4 v) { return __builtin_bit_cast(bf16x8, v); }

// f32 -> packed (hi_bf16 << 16) | lo_bf16  (truncation split, err ~2^-16|x|)
__device__ __forceinline__ unsigned packsplit(float x) {
    const unsigned u  = __float_as_uint(x);
    const unsigned hi = u & 0xFFFF0000u;
    const float lof   = x - __uint_as_float(hi);
    return hi | (__float_as_uint(lof) >> 16);
}

struct u32pair { unsigned h, l; };

__device__ __forceinline__ u32pair splitpair(float f0, float f1) {
    const unsigned u0 = __float_as_uint(f0), u1 = __float_as_uint(f1);
    u32pair r;
    r.h = __builtin_amdgcn_perm(u1, u0, 0x07060302u);
    const float l0 = f0 - __uint_as_float(u0 & 0xFFFF0000u);
    const float l1 = f1 - __uint_as_float(u1 & 0xFFFF0000u);
    r.l = __builtin_amdgcn_perm(__float_as_uint(l1), __float_as_uint(l0), 0x07060302u);
    return r;
}

// 8 packed u32 (two aligned quads) -> (hi,lo) MFMA operand pair
__device__ __forceinline__ void unpack2q(const u32x4 q0, const u32x4 q1,
                                         u32x4& hi, u32x4& lo) {
    hi[0] = __builtin_amdgcn_perm(q0[1], q0[0], 0x07060302u);
    lo[0] = __builtin_amdgcn_perm(q0[1], q0[0], 0x05040100u);
    hi[1] = __builtin_amdgcn_perm(q0[3], q0[2], 0x07060302u);
    lo[1] = __builtin_amdgcn_perm(q0[3], q0[2], 0x05040100u);
    hi[2] = __builtin_amdgcn_perm(q1[1], q1[0], 0x07060302u);
    lo[2] = __builtin_amdgcn_perm(q1[1], q1[0], 0x05040100u);
    hi[3] = __builtin_amdgcn_perm(q1[3], q1[2], 0x07060302u);
    lo[3] = __builtin_amdgcn_perm(q1[3], q1[2], 0x05040100u);
}

__device__ __forceinline__ void split8v(const float* xv, u32x4& hi, u32x4& lo) {
    #pragma unroll
    for (int w2 = 0; w2 < 4; ++w2) {
        const u32pair r = splitpair(xv[2*w2], xv[2*w2+1]);
        hi[w2] = r.h;
        lo[w2] = r.l;
    }
}

// ---- prep: split W into MFMA-A-fragment-ordered hi/lo arrays in ws.
__global__ void split_w_kernel(const float* __restrict__ wmat,
                               unsigned* __restrict__ whiG,
                               unsigned* __restrict__ wloG) {
    const int idx = blockIdx.x * 256 + threadIdx.x;   // 2048 total
    const int mt = idx >> 9, s = (idx >> 6) & 7, l = idx & 63;
    const int k = mt * 16 + (l & 15);
    const int cb = s * 32 + 8 * (l >> 4);
    const float* wr = wmat + k * 256 + cb;
    const float4 f0 = *(const float4*)wr;
    const float4 f1 = *(const float4*)(wr + 4);
    const float xv[8] = {f0.x, f0.y, f0.z, f0.w, f1.x, f1.y, f1.z, f1.w};
    u32x4 hi, lo; split8v(xv, hi, lo);
    *(u32x4*)(whiG + idx * 4) = hi;
    *(u32x4*)(wloG + idx * 4) = lo;
}

// ================= P1: logits + softmax -> packed a' = a*rn ================
__global__ __launch_bounds__(256, 4) void netvlad_p1(
    const float* __restrict__ x,
    const unsigned* __restrict__ whiG, const unsigned* __restrict__ wloG,
    const float* __restrict__ bias, unsigned* __restrict__ aG,
    float* __restrict__ asum_part) {

    __shared__ float asum_lds[4][64];
    const int t = threadIdx.x;
    const int w = t >> 6, l = t & 63;
    const int l15 = l & 15, lg4 = l >> 4;
    const int n = blockIdx.x & 127, e = blockIdx.x >> 7;
    const size_t ximg = (size_t)n * 256 * 1024;
    const int p0 = e * 128;
    const int cs = lg4 * 8;

    f32x4 acc1[4][2];
    #pragma unroll
    for (int i = 0; i < 4; ++i) {
        acc1[i][0] = f32x4{0.f, 0.f, 0.f, 0.f};
        acc1[i][1] = f32x4{0.f, 0.f, 0.f, 0.f};
    }
    float ssa[2] = {0.f, 0.f};

    #define P1_ADDR(st_) (x + ximg + (size_t)(((st_) >> 1) * 32 + cs) * 1024 \
                          + p0 + (2 * w + ((st_) & 1)) * 16 + l15)
    float nxv[8];
    {
        const float* bp = P1_ADDR(0);
        #pragma unroll
        for (int j = 0; j < 8; ++j) nxv[j] = bp[(size_t)j * 1024];
    }
    u32x4 wh[4], wl[4];
    #pragma unroll
    for (int st = 0; st < 16; ++st) {
        const int s = st >> 1, ntl = st & 1;
        float xv[8];
        #pragma unroll
        for (int j = 0; j < 8; ++j) xv[j] = nxv[j];
        if (st < 15) {
            const float* bp = P1_ADDR(st + 1);
            #pragma unroll
            for (int j = 0; j < 8; ++j) nxv[j] = bp[(size_t)j * 1024];
        }
        if (ntl == 0) {
            #pragma unroll
            for (int mt = 0; mt < 4; ++mt) {
                const int fo = ((mt * 8 + s) * 64 + l) * 4;
                wh[mt] = *(const u32x4*)(whiG + fo);
                wl[mt] = *(const u32x4*)(wloG + fo);
            }
        }
        #pragma unroll
        for (int j = 0; j < 8; ++j) ssa[ntl] = fmaf(xv[j], xv[j], ssa[ntl]);
        u32x4 bhi, blo; split8v(xv, bhi, blo);
        #pragma unroll
        for (int mt = 0; mt < 4; ++mt) {
            acc1[mt][ntl] = MFMA(as_bf(wh[mt]), as_bf(bhi), acc1[mt][ntl]);
            acc1[mt][ntl] = MFMA(as_bf(wh[mt]), as_bf(blo), acc1[mt][ntl]);
            acc1[mt][ntl] = MFMA(as_bf(wl[mt]), as_bf(bhi), acc1[mt][ntl]);
        }
    }
    #pragma unroll
    for (int ntl = 0; ntl < 2; ++ntl) {
        ssa[ntl] += __shfl_xor(ssa[ntl], 16);
        ssa[ntl] += __shfl_xor(ssa[ntl], 32);
    }

    f32x4 biasv[4];
    #pragma unroll
    for (int mt = 0; mt < 4; ++mt)
        biasv[mt] = *(const f32x4*)(bias + mt * 16 + 4 * lg4);

    float asum_loc[16];
    #pragma unroll
    for (int i = 0; i < 16; ++i) asum_loc[i] = 0.f;

    #pragma unroll
    for (int ntl = 0; ntl < 2; ++ntl) {
        const int p = p0 + (2 * w + ntl) * 16 + l15;
        const float rn = 1.f / fmaxf(sqrtf(ssa[ntl]), EPSF);
        float lgv[16];
        #pragma unroll
        for (int mt = 0; mt < 4; ++mt)
            #pragma unroll
            for (int r = 0; r < 4; ++r)
                lgv[mt * 4 + r] = fmaf(acc1[mt][ntl][r], rn, biasv[mt][r]);
        float mx = lgv[0];
        #pragma unroll
        for (int i = 1; i < 16; ++i) mx = fmaxf(mx, lgv[i]);
        mx = fmaxf(mx, __shfl_xor(mx, 16));
        mx = fmaxf(mx, __shfl_xor(mx, 32));
        float den = 0.f;
        #pragma unroll
        for (int i = 0; i < 16; ++i) { lgv[i] = __expf(lgv[i] - mx); den += lgv[i]; }
        den += __shfl_xor(den, 16);
        den += __shfl_xor(den, 32);
        const float inv = 1.f / den;
        #pragma unroll
        for (int mt = 0; mt < 4; ++mt)
            #pragma unroll
            for (int r = 0; r < 4; ++r) {
                const float av = lgv[mt * 4 + r] * inv;      // raw a
                asum_loc[mt * 4 + r] += av;
                aG[((size_t)n * 64 + mt * 16 + 4 * lg4 + r) * 1024 + p] =
                    packsplit(av * rn);                      // a' = a*rn
            }
    }

    #pragma unroll
    for (int i = 0; i < 16; ++i) {
        float s = asum_loc[i];
        s += __shfl_xor(s, 1);
        s += __shfl_xor(s, 2);
        s += __shfl_xor(s, 4);
        s += __shfl_xor(s, 8);
        if (l15 == 0) asum_lds[w][(i >> 2) * 16 + 4 * lg4 + (i & 3)] = s;
    }
    __syncthreads();
    if (t < 64)
        asum_part[((size_t)n * 8 + e) * 64 + t] =
            asum_lds[0][t] + asum_lds[1][t] + asum_lds[2][t] + asum_lds[3][t];
}

// ===== P2: agg partial = a' @ x^T; global_load_lds DMA-staged slabs =====
__global__ __launch_bounds__(256, 4) void netvlad_p2(
    const float* __restrict__ x, const unsigned* __restrict__ aG,
    float* __restrict__ out0, float* __restrict__ out1) {

    // slab layouts (per buffer): [64 rows][32 u32] linear; quad q of row r
    // holds ORIGINAL quad q^(r&7)  (inverse-swizzled at the global source).
    __shared__ __align__(16) unsigned xs[2][2048];   // raw fp32 x
    __shared__ __align__(16) unsigned as2[2][2048];  // packed a'

    const int t = threadIdx.x;
    const int w = t >> 6, l = t & 63;
    const int l15 = l & 15, lg4 = l >> 4;
    const int n = blockIdx.x & 127;
    const int z = blockIdx.x >> 7;
    const int cq = z & 3, ph = z >> 2;
    const size_t ximg = (size_t)n * 256 * 1024;
    const int c0 = cq * 64;                // block's 64-channel quarter
    const int pb0 = ph * 512;              // pixel-half base

    // staging addresses: wave-instr i covers LDS quads Q = w*128+i*64+l
    const float* srcx[2];
    const unsigned* srca[2];
    unsigned ldsq[2];                      // wave-uniform dst base (u32 idx)
    #pragma unroll
    for (int i = 0; i < 2; ++i) {
        const int Q = w * 128 + i * 64 + l;
        const int row = Q >> 3, q = Q & 7;
        const int qs = q ^ (row & 7);      // inverse swizzle at source
        srcx[i] = x + ximg + (size_t)(c0 + row) * 1024 + pb0 + qs * 4;
        srca[i] = aG + ((size_t)n * 64 + row) * 1024 + pb0 + qs * 4;
        ldsq[i] = (unsigned)((w * 128 + i * 64) * 4);
    }

    #define P2DMA(s_, b_) { _Pragma("unroll")                                 \
        for (int i = 0; i < 2; ++i) {                                         \
            __builtin_amdgcn_global_load_lds(                                 \
                (const __attribute__((address_space(1))) void*)(srcx[i] + (s_) * 32), \
                (__attribute__((address_space(3))) void*)(&xs[b_][ldsq[i]]),  \
                16, 0, 0);                                                    \
            __builtin_amdgcn_global_load_lds(                                 \
                (const __attribute__((address_space(1))) void*)(srca[i] + (s_) * 32), \
                (__attribute__((address_space(3))) void*)(&as2[b_][ldsq[i]]), \
                16, 0, 0);                                                    \
        } }

    f32x4 acc[4];
    #pragma unroll
    for (int mt = 0; mt < 4; ++mt) acc[mt] = f32x4{0.f, 0.f, 0.f, 0.f};

    // swizzled read offsets (u32): quad (lg4*2 + {0,1}) ^ (row&7), row&7 = l15&7
    const int sA = (((lg4 * 2)     ^ (l15 & 7)) << 2);
    const int sB = (((lg4 * 2 + 1) ^ (l15 & 7)) << 2);
    const int rx = w * 16 + l15;           // wave's channel row in slab

    P2DMA(0, 0);
    #pragma unroll
    for (int ks = 0; ks < 16; ++ks) {
        __syncthreads();                   // slab ks DMA drained; dbuf free
        if (ks < 15) P2DMA(ks + 1, (ks + 1) & 1);   // overlaps compute below
        const unsigned* xb = xs[ks & 1];
        const unsigned* ab = as2[ks & 1];

        const u32x4 fx0 = *(const u32x4*)(xb + rx * 32 + sA);
        const u32x4 fx1 = *(const u32x4*)(xb + rx * 32 + sB);
        float xv[8];
        xv[0] = __uint_as_float(fx0[0]); xv[1] = __uint_as_float(fx0[1]);
        xv[2] = __uint_as_float(fx0[2]); xv[3] = __uint_as_float(fx0[3]);
        xv[4] = __uint_as_float(fx1[0]); xv[5] = __uint_as_float(fx1[1]);
        xv[6] = __uint_as_float(fx1[2]); xv[7] = __uint_as_float(fx1[3]);
        u32x4 bhi, blo; split8v(xv, bhi, blo);

        #pragma unroll
        for (int mt = 0; mt < 4; ++mt) {
            const int ra = mt * 16 + l15;
            const u32x4 pa  = *(const u32x4*)(ab + ra * 32 + sA);
            const u32x4 pbq = *(const u32x4*)(ab + ra * 32 + sB);
            u32x4 ahi, alo; unpack2q(pa, pbq, ahi, alo);
            acc[mt] = MFMA(as_bf(ahi), as_bf(bhi), acc[mt]);
            acc[mt] = MFMA(as_bf(ahi), as_bf(blo), acc[mt]);
            acc[mt] = MFMA(as_bf(alo), as_bf(bhi), acc[mt]);
        }
    }

    float* op = (ph ? out1 : out0) + (size_t)n * 16384;
    #pragma unroll
    for (int mt = 0; mt < 4; ++mt)
        #pragma unroll
        for (int r = 0; r < 4; ++r)
            op[(mt * 16 + 4 * lg4 + r) * 256 + c0 + w * 16 + l15] = acc[mt][r];
}

__global__ __launch_bounds__(256) void netvlad_epi(
    float* __restrict__ out, const float* __restrict__ out1,
    const float* __restrict__ asum_part, const float* __restrict__ cent) {
    __shared__ float wred[4];
    __shared__ float gs_sh;
    const int n = blockIdx.x;
    const int t = threadIdx.x;
    const int k = t >> 2;          // 4 threads per cluster row
    const int q = t & 3;
    float* op = out + (size_t)n * 16384 + k * 256 + q * 64;
    const float* o1 = out1 + (size_t)n * 16384 + k * 256 + q * 64;
    const float* cp = cent + k * 256 + q * 64;
    float as = 0.f;
    #pragma unroll
    for (int e2 = 0; e2 < 8; ++e2)
        as += asum_part[((size_t)n * 8 + e2) * 64 + k];

    float v[64];
    float ss = 0.f;
    #pragma unroll
    for (int i = 0; i < 64; i += 4) {
        const float4 a0 = *(const float4*)&op[i];
        const float4 a1 = *(const float4*)&o1[i];
        const float4 cv = *(const float4*)&cp[i];
        v[i+0] = fmaf(-as, cv.x, a0.x + a1.x);
        v[i+1] = fmaf(-as, cv.y, a0.y + a1.y);
        v[i+2] = fmaf(-as, cv.z, a0.z + a1.z);
        v[i+3] = fmaf(-as, cv.w, a0.w + a1.w);
        ss = fmaf(v[i+0], v[i+0], ss);
        ss = fmaf(v[i+1], v[i+1], ss);
        ss = fmaf(v[i+2], v[i+2], ss);
        ss = fmaf(v[i+3], v[i+3], ss);
    }
    ss += __shfl_xor(ss, 1);
    ss += __shfl_xor(ss, 2);
    const float iscale = 1.f / fmaxf(sqrtf(ss), EPSF);

    float gsum = (q == 0) ? ss * iscale * iscale : 0.f;
    #pragma unroll
    for (int off = 4; off < 64; off <<= 1) gsum += __shfl_xor(gsum, off);
    if ((t & 63) == 0) wred[t >> 6] = gsum;
    __syncthreads();
    if (t == 0) {
        const float tot = wred[0] + wred[1] + wred[2] + wred[3];
        gs_sh = 1.f / fmaxf(sqrtf(tot), EPSF);
    }
    __syncthreads();
    const float fs = iscale * gs_sh;
    #pragma unroll
    for (int i = 0; i < 64; i += 4) {
        float4 w4;
        w4.x = v[i+0] * fs; w4.y = v[i+1] * fs;
        w4.z = v[i+2] * fs; w4.w = v[i+3] * fs;
        *(float4*)&op[i] = w4;
    }
}

extern "C" void kernel_launch(void* const* d_in, const int* in_sizes, int n_in,
                              void* d_out, int out_size, void* d_ws, size_t ws_size,
                              hipStream_t stream) {
    (void)in_sizes; (void)n_in; (void)out_size; (void)ws_size;
    const float* x    = (const float*)d_in[0];
    const float* wmat = (const float*)d_in[1];
    const float* b    = (const float*)d_in[2];
    const float* cent = (const float*)d_in[3];
    float* out = (float*)d_out;
    // ws layout (u32 units): whiG 8192 | wloG 8192 | asum_part 65536 |
    //                        aG 8388608 | out1 2097152   (~42.3 MB)
    unsigned* whiG = (unsigned*)d_ws;
    unsigned* wloG = whiG + 8192;
    float* asum_part = (float*)(whiG + 16384);
    unsigned* aG   = whiG + 16384 + 65536;
    float* out1    = (float*)(aG + 8388608);

    split_w_kernel<<<8, 256, 0, stream>>>(wmat, whiG, wloG);
    netvlad_p1<<<1024, 256, 0, stream>>>(x, whiG, wloG, b, aG, asum_part);
    netvlad_p2<<<1024, 256, 0, stream>>>(x, aG, out, out1);
    netvlad_epi<<<128, 256, 0, stream>>>(out, out1, asum_part, cent);
}